// Round 1
// baseline (1242.153 us; speedup 1.0000x reference)
//
#include <hip/hip_runtime.h>
#include <cstdint>

#define NB 8
#define NC 128
#define NPIX 4096
#define NGROUP 8
#define CPG 16
#define EPS_GN 1e-5f
#define SCALE 0.08838834764831845f  // 128^-0.5

// ---------------- K1: group-norm stats (mean, rstd per (b,g)) ----------------
__global__ __launch_bounds__(256) void k_gn_stats(const float* __restrict__ x,
                                                  float* __restrict__ stats) {
  int blk = blockIdx.x;  // b*NGROUP + g ; group data is contiguous: 16*4096 floats
  const float4* base = (const float4*)(x + (size_t)blk * CPG * NPIX);
  float s = 0.f, ss = 0.f;
  for (int i = threadIdx.x; i < CPG * NPIX / 4; i += 256) {
    float4 v = base[i];
    s  += v.x + v.y + v.z + v.w;
    ss += v.x * v.x + v.y * v.y + v.z * v.z + v.w * v.w;
  }
#pragma unroll
  for (int off = 32; off >= 1; off >>= 1) {
    s  += __shfl_down(s, off);
    ss += __shfl_down(ss, off);
  }
  __shared__ float red[8];
  int wid = threadIdx.x >> 6;
  if ((threadIdx.x & 63) == 0) { red[wid] = s; red[4 + wid] = ss; }
  __syncthreads();
  if (threadIdx.x == 0) {
    float S  = red[0] + red[1] + red[2] + red[3];
    float SS = red[4] + red[5] + red[6] + red[7];
    float mean = S * (1.f / (CPG * NPIX));
    float var  = SS * (1.f / (CPG * NPIX)) - mean * mean;
    stats[blk * 2]     = mean;
    stats[blk * 2 + 1] = rsqrtf(var + EPS_GN);
  }
}

// ---------------- K2: QKV 1x1 conv (GEMM) with fused group-norm --------------
// qkv[b][o][p] = sum_c w[o][c] * hn[b][c][p] + bias[o],  hn = s_c*x + t_c
__global__ __launch_bounds__(256) void k_qkv(const float* __restrict__ x,
                                             const float* __restrict__ stats,
                                             const float* __restrict__ gamma,
                                             const float* __restrict__ beta,
                                             const float* __restrict__ w,
                                             const float* __restrict__ bias,
                                             float* __restrict__ qkv) {
  __shared__ float As[64][129];   // w rows [o][k], pad 129 -> conflict-free col reads
  __shared__ float Bs[128][64];   // normalized x tile [c][p]
  __shared__ float sArr[128], tArr[128];
  int b = blockIdx.z, o0 = blockIdx.y * 64, p0 = blockIdx.x * 64;
  int tid = threadIdx.x;
  if (tid < 128) {
    int g = tid >> 4;
    float mean = stats[(b * NGROUP + g) * 2];
    float rstd = stats[(b * NGROUP + g) * 2 + 1];
    float sc = rstd * gamma[tid];
    sArr[tid] = sc;
    tArr[tid] = beta[tid] - mean * sc;
  }
  for (int i = tid; i < 64 * 128; i += 256) {
    As[i >> 7][i & 127] = w[(size_t)o0 * 128 + i];  // = w[(o0+(i>>7))*128 + (i&127)]
  }
  __syncthreads();
  const float* xb = x + (size_t)b * NC * NPIX;
  for (int i = tid; i < 128 * 64; i += 256) {
    int c = i >> 6, p = i & 63;
    Bs[c][p] = sArr[c] * xb[(size_t)c * NPIX + p0 + p] + tArr[c];
  }
  __syncthreads();
  int ty = tid >> 4, tx = tid & 15;  // o = o0+ty*4.., p = p0+tx*4..
  float acc[4][4] = {};
  for (int k = 0; k < 128; ++k) {
    float4 bv = *(const float4*)&Bs[k][tx * 4];
#pragma unroll
    for (int i = 0; i < 4; ++i) {
      float a = As[ty * 4 + i][k];
      acc[i][0] += a * bv.x; acc[i][1] += a * bv.y;
      acc[i][2] += a * bv.z; acc[i][3] += a * bv.w;
    }
  }
#pragma unroll
  for (int i = 0; i < 4; ++i) {
    int o = o0 + ty * 4 + i;
    float bb = bias[o];
    float4 r = make_float4(acc[i][0] + bb, acc[i][1] + bb, acc[i][2] + bb, acc[i][3] + bb);
    *(float4*)&qkv[((size_t)b * 384 + o) * NPIX + p0 + tx * 4] = r;
  }
}

// ---------------- K3: flash attention, QT=64 per block, KT=32 ----------------
__global__ __launch_bounds__(256) void k_attn(const float* __restrict__ qkv,
                                              float* __restrict__ attout) {
  __shared__ float qs[128][64];    // q[c][qi] * scale
  __shared__ float ks[128][32];    // k[c][j]
  __shared__ float vsT[32][132];   // v transposed [j][c], pad 132 (16B-aligned rows)
  __shared__ float sS[64][33];     // scores / p, pad 33
  __shared__ float mState[64], lState[64], alphaArr[64];
  int b = blockIdx.y;
  int q0 = blockIdx.x * 64;
  int tid = threadIdx.x;
  const float* qg = qkv + (size_t)b * 384 * NPIX;
  const float* kg = qg + (size_t)128 * NPIX;
  const float* vg = qg + (size_t)256 * NPIX;
  for (int i = tid; i < 128 * 64; i += 256) {
    int c = i >> 6, p = i & 63;
    qs[c][p] = qg[(size_t)c * NPIX + q0 + p] * SCALE;
  }
  if (tid < 64) { mState[tid] = -1e30f; lState[tid] = 0.f; }
  int qgrp = tid & 15;   // queries qgrp*4 .. +4 (acc ownership)
  int cgrp = tid >> 4;   // channels cgrp*8 .. +8
  int srow = tid >> 2;   // softmax row
  int ssub = tid & 3;    // softmax sub-range (8 j each)
  float acc[8][4];
#pragma unroll
  for (int c = 0; c < 8; ++c)
#pragma unroll
    for (int i = 0; i < 4; ++i) acc[c][i] = 0.f;

  for (int j0 = 0; j0 < NPIX; j0 += 32) {
    __syncthreads();  // protect ks/vsT/sS from previous iteration readers
    for (int i = tid; i < 128 * 32; i += 256) {
      int c = i >> 5, j = i & 31;
      float kvv = kg[(size_t)c * NPIX + j0 + j];
      float vvv = vg[(size_t)c * NPIX + j0 + j];
      ks[c][j] = kvv;
      vsT[j][c] = vvv;
    }
    __syncthreads();
    // ---- scores: each thread 4q x 2j ----
    {
      float sa[4][2];
#pragma unroll
      for (int i = 0; i < 4; ++i) { sa[i][0] = 0.f; sa[i][1] = 0.f; }
      int qq = qgrp * 4;
      int jj = (tid >> 4) * 2;
      for (int c = 0; c < 128; ++c) {
        float4 qv = *(const float4*)&qs[c][qq];
        float2 kv = *(const float2*)&ks[c][jj];
        sa[0][0] += qv.x * kv.x; sa[0][1] += qv.x * kv.y;
        sa[1][0] += qv.y * kv.x; sa[1][1] += qv.y * kv.y;
        sa[2][0] += qv.z * kv.x; sa[2][1] += qv.z * kv.y;
        sa[3][0] += qv.w * kv.x; sa[3][1] += qv.w * kv.y;
      }
#pragma unroll
      for (int i = 0; i < 4; ++i) {
        sS[qq + i][jj]     = sa[i][0];
        sS[qq + i][jj + 1] = sa[i][1];
      }
    }
    __syncthreads();
    // ---- online softmax: 4 threads per row, 8 j each ----
    {
      float pm = -1e30f;
#pragma unroll
      for (int j = 0; j < 8; ++j) pm = fmaxf(pm, sS[srow][ssub * 8 + j]);
      pm = fmaxf(pm, __shfl_xor(pm, 1));
      pm = fmaxf(pm, __shfl_xor(pm, 2));
      float mold = mState[srow];
      float mnew = fmaxf(mold, pm);
      float lsum = 0.f;
#pragma unroll
      for (int j = 0; j < 8; ++j) {
        float p = __expf(sS[srow][ssub * 8 + j] - mnew);
        sS[srow][ssub * 8 + j] = p;
        lsum += p;
      }
      lsum += __shfl_xor(lsum, 1);
      lsum += __shfl_xor(lsum, 2);
      if (ssub == 0) {
        alphaArr[srow] = __expf(mold - mnew);
        lState[srow] = lState[srow] * __expf(mold - mnew) + lsum;
        mState[srow] = mnew;
      }
    }
    __syncthreads();
    // ---- accumulator update: thread owns 8 channels x 4 queries ----
    {
      int qq = qgrp * 4;
      float al[4];
#pragma unroll
      for (int i = 0; i < 4; ++i) al[i] = alphaArr[qq + i];
#pragma unroll
      for (int c = 0; c < 8; ++c)
#pragma unroll
        for (int i = 0; i < 4; ++i) acc[c][i] *= al[i];
      for (int j = 0; j < 32; ++j) {
        float p0v = sS[qq][j], p1v = sS[qq + 1][j];
        float p2v = sS[qq + 2][j], p3v = sS[qq + 3][j];
        float4 v0 = *(const float4*)&vsT[j][cgrp * 8];
        float4 v1 = *(const float4*)&vsT[j][cgrp * 8 + 4];
        float vv[8] = {v0.x, v0.y, v0.z, v0.w, v1.x, v1.y, v1.z, v1.w};
#pragma unroll
        for (int c = 0; c < 8; ++c) {
          acc[c][0] += vv[c] * p0v;
          acc[c][1] += vv[c] * p1v;
          acc[c][2] += vv[c] * p2v;
          acc[c][3] += vv[c] * p3v;
        }
      }
    }
  }
  __syncthreads();
  float inv[4];
#pragma unroll
  for (int i = 0; i < 4; ++i) inv[i] = 1.f / lState[qgrp * 4 + i];
#pragma unroll
  for (int c = 0; c < 8; ++c) {
    int ch = cgrp * 8 + c;
    float4 r = make_float4(acc[c][0] * inv[0], acc[c][1] * inv[1],
                           acc[c][2] * inv[2], acc[c][3] * inv[3]);
    *(float4*)&attout[((size_t)b * NC + ch) * NPIX + q0 + qgrp * 4] = r;
  }
}

// ---------------- K4: proj 1x1 conv + bias + residual, in place on d_out -----
// Each block handles ALL 128 output rows for its 64-pixel column slice, so the
// in-place read/overwrite of d_out is block-local (no inter-block hazard).
__global__ __launch_bounds__(256) void k_proj(const float* __restrict__ x,
                                              const float* __restrict__ w,
                                              const float* __restrict__ bias,
                                              float* __restrict__ io) {
  __shared__ float As[128][129];  // w[o][k], pad 129
  __shared__ float Bs[128][64];   // attout tile [c][p]
  int b = blockIdx.y, p0 = blockIdx.x * 64;
  int tid = threadIdx.x;
  for (int i = tid; i < 128 * 128; i += 256) {
    As[i >> 7][i & 127] = w[i];
  }
  float* iob = io + (size_t)b * NC * NPIX;
  for (int i = tid; i < 128 * 64; i += 256) {
    int c = i >> 6, p = i & 63;
    Bs[c][p] = iob[(size_t)c * NPIX + p0 + p];
  }
  __syncthreads();
  int ty = tid >> 4, tx = tid & 15;  // o = ty*8.., p = tx*4..
  float acc[8][4] = {};
  for (int k = 0; k < 128; ++k) {
    float4 bv = *(const float4*)&Bs[k][tx * 4];
#pragma unroll
    for (int i = 0; i < 8; ++i) {
      float a = As[ty * 8 + i][k];
      acc[i][0] += a * bv.x; acc[i][1] += a * bv.y;
      acc[i][2] += a * bv.z; acc[i][3] += a * bv.w;
    }
  }
  const float* xb = x + (size_t)b * NC * NPIX;
#pragma unroll
  for (int i = 0; i < 8; ++i) {
    int o = ty * 8 + i;
    float bb = bias[o];
    size_t base = (size_t)o * NPIX + p0 + tx * 4;
    float4 xr = *(const float4*)&xb[base];
    float4 r = make_float4(acc[i][0] + bb + xr.x, acc[i][1] + bb + xr.y,
                           acc[i][2] + bb + xr.z, acc[i][3] + bb + xr.w);
    *(float4*)&iob[base] = r;
  }
}

extern "C" void kernel_launch(void* const* d_in, const int* in_sizes, int n_in,
                              void* d_out, int out_size, void* d_ws, size_t ws_size,
                              hipStream_t stream) {
  const float* x      = (const float*)d_in[0];
  const float* gamma  = (const float*)d_in[1];
  const float* beta   = (const float*)d_in[2];
  const float* w_qkv  = (const float*)d_in[3];
  const float* b_qkv  = (const float*)d_in[4];
  const float* w_proj = (const float*)d_in[5];
  const float* b_proj = (const float*)d_in[6];
  float* out = (float*)d_out;
  float* ws  = (float*)d_ws;

  float* stats = ws;        // 128 floats
  float* qkv   = ws + 256;  // 8*384*4096 floats (~48 MB); total ws need ~50.3 MB

  hipLaunchKernelGGL(k_gn_stats, dim3(NB * NGROUP), dim3(256), 0, stream, x, stats);
  hipLaunchKernelGGL(k_qkv, dim3(NPIX / 64, 6, NB), dim3(256), 0, stream,
                     x, stats, gamma, beta, w_qkv, b_qkv, qkv);
  hipLaunchKernelGGL(k_attn, dim3(NPIX / 64, NB), dim3(256), 0, stream, qkv, out);
  hipLaunchKernelGGL(k_proj, dim3(NPIX / 64, NB), dim3(256), 0, stream,
                     x, w_proj, b_proj, out);
}

// Round 2
// 269.312 us; speedup vs baseline: 4.6123x; 4.6123x over previous
//
#include <hip/hip_runtime.h>
#include <cstdint>

#define NB 8
#define NC 128
#define NPIX 4096
#define NGROUP 8
#define CPG 16
#define EPS_GN 1e-5f
#define SCALE 0.08838834764831845f  // 128^-0.5

typedef __attribute__((ext_vector_type(8))) short short8;
typedef __attribute__((ext_vector_type(16))) float f32x16;

__device__ __forceinline__ unsigned bfr(float f) {  // float -> bf16 bits (RNE)
  unsigned u = __builtin_bit_cast(unsigned, f);
  return (u + 0x7fffu + ((u >> 16) & 1u)) >> 16;
}
__device__ __forceinline__ unsigned packbf(float lo, float hi) {
  return bfr(lo) | (bfr(hi) << 16);
}

// ---------------- K1: group-norm stats (mean, rstd per (b,g)) ----------------
__global__ __launch_bounds__(256) void k_gn_stats(const float* __restrict__ x,
                                                  float* __restrict__ stats) {
  int blk = blockIdx.x;
  const float4* base = (const float4*)(x + (size_t)blk * CPG * NPIX);
  float s = 0.f, ss = 0.f;
  for (int i = threadIdx.x; i < CPG * NPIX / 4; i += 256) {
    float4 v = base[i];
    s  += v.x + v.y + v.z + v.w;
    ss += v.x * v.x + v.y * v.y + v.z * v.z + v.w * v.w;
  }
#pragma unroll
  for (int off = 32; off >= 1; off >>= 1) {
    s  += __shfl_down(s, off);
    ss += __shfl_down(ss, off);
  }
  __shared__ float red[8];
  int wid = threadIdx.x >> 6;
  if ((threadIdx.x & 63) == 0) { red[wid] = s; red[4 + wid] = ss; }
  __syncthreads();
  if (threadIdx.x == 0) {
    float S  = red[0] + red[1] + red[2] + red[3];
    float SS = red[4] + red[5] + red[6] + red[7];
    float mean = S * (1.f / (CPG * NPIX));
    float var  = SS * (1.f / (CPG * NPIX)) - mean * mean;
    stats[blk * 2]     = mean;
    stats[blk * 2 + 1] = rsqrtf(var + EPS_GN);
  }
}

// ---------------- K2: QKV GEMM with fused group-norm; bf16 outputs -----------
// qT[b][n][c] = (q + bias)*SCALE ; kT[b][n][c] = k + bias ; vB[b][c][n] = v + bias
__global__ __launch_bounds__(256) void k_qkv(const float* __restrict__ x,
                                             const float* __restrict__ stats,
                                             const float* __restrict__ gamma,
                                             const float* __restrict__ beta,
                                             const float* __restrict__ w,
                                             const float* __restrict__ bias,
                                             ushort* __restrict__ qT,
                                             ushort* __restrict__ kT,
                                             ushort* __restrict__ vB) {
  __shared__ float As[64][129];
  __shared__ float Bs[128][64];
  __shared__ float sArr[128], tArr[128];
  int b = blockIdx.z, o0 = blockIdx.y * 64, p0 = blockIdx.x * 64;
  int tid = threadIdx.x;
  if (tid < 128) {
    int g = tid >> 4;
    float mean = stats[(b * NGROUP + g) * 2];
    float rstd = stats[(b * NGROUP + g) * 2 + 1];
    float sc = rstd * gamma[tid];
    sArr[tid] = sc;
    tArr[tid] = beta[tid] - mean * sc;
  }
  for (int i = tid; i < 64 * 128; i += 256) {
    As[i >> 7][i & 127] = w[(size_t)o0 * 128 + i];
  }
  __syncthreads();
  const float* xb = x + (size_t)b * NC * NPIX;
  for (int i = tid; i < 128 * 64; i += 256) {
    int c = i >> 6, p = i & 63;
    Bs[c][p] = sArr[c] * xb[(size_t)c * NPIX + p0 + p] + tArr[c];
  }
  __syncthreads();
  int ty = tid & 15, tx = tid >> 4;  // o = o0+ty*4.., p = p0+tx*4..
  float acc[4][4] = {};
  for (int k = 0; k < 128; ++k) {
    float4 bv = *(const float4*)&Bs[k][tx * 4];
#pragma unroll
    for (int i = 0; i < 4; ++i) {
      float a = As[ty * 4 + i][k];
      acc[i][0] += a * bv.x; acc[i][1] += a * bv.y;
      acc[i][2] += a * bv.z; acc[i][3] += a * bv.w;
    }
  }
  float bb[4];
#pragma unroll
  for (int i = 0; i < 4; ++i) bb[i] = bias[o0 + ty * 4 + i];

  if (o0 < 256) {  // Q or K: transposed bf16 store qT/kT[b][p][c]
    const bool isQ = (o0 < 128);
    ushort* dstT = isQ ? qT : kT;
    int osec = isQ ? o0 : (o0 - 128);
    float sc = isQ ? SCALE : 1.0f;
#pragma unroll
    for (int pp = 0; pp < 4; ++pp) {
      int p = p0 + tx * 4 + pp;
      ushort4 wv;
      wv.x = (ushort)bfr((acc[0][pp] + bb[0]) * sc);
      wv.y = (ushort)bfr((acc[1][pp] + bb[1]) * sc);
      wv.z = (ushort)bfr((acc[2][pp] + bb[2]) * sc);
      wv.w = (ushort)bfr((acc[3][pp] + bb[3]) * sc);
      *(ushort4*)&dstT[(((size_t)b << 12) + p) * 128 + osec + ty * 4] = wv;
    }
  } else {  // V: vB[b][c][p] bf16
#pragma unroll
    for (int i = 0; i < 4; ++i) {
      int c = o0 - 256 + ty * 4 + i;
      ushort4 wv;
      wv.x = (ushort)bfr(acc[i][0] + bb[i]);
      wv.y = (ushort)bfr(acc[i][1] + bb[i]);
      wv.z = (ushort)bfr(acc[i][2] + bb[i]);
      wv.w = (ushort)bfr(acc[i][3] + bb[i]);
      *(ushort4*)&vB[(((size_t)(b * 128 + c)) << 12) + p0 + tx * 4] = wv;
    }
  }
}

// ---------------- K3: MFMA flash attention -----------------------------------
// 2 waves/block, 32 queries/wave, KV tile 64. Swapped QK^T: D[j][q].
__device__ __forceinline__ void stage_tiles(const ushort* __restrict__ kT,
                                            const ushort* __restrict__ vB,
                                            ushort* lds, int b, int j0, int tid) {
#pragma unroll
  for (int u = 0; u < 8; ++u) {          // Ks: 64 rows x 16 chunks (16B)
    int id = tid + u * 128;
    int row = id >> 4, ch = id & 15;
    const ushort* src = kT + (((size_t)b << 12) + j0 + row) * 128 + ((ch ^ (row & 7)) << 3);
    *(uint4*)&lds[id << 3] = *(const uint4*)src;
  }
#pragma unroll
  for (int u = 0; u < 8; ++u) {          // Vs: 128 rows x 8 chunks
    int id = tid + u * 128;
    int row = id >> 3, ch = id & 7;
    const ushort* src = vB + (((size_t)(b * 128 + row)) << 12) + j0 + ((ch ^ (row & 7)) << 3);
    *(uint4*)&lds[8192 + (id << 3)] = *(const uint4*)src;
  }
}

__global__ __launch_bounds__(128) void k_attn(const ushort* __restrict__ qT,
                                              const ushort* __restrict__ kT,
                                              const ushort* __restrict__ vB,
                                              float* __restrict__ attOut) {
  __shared__ ushort lds[16384];  // Ks [0..8191], Vs [8192..16383]
  int tid = threadIdx.x;
  int b = blockIdx.x;            // batch on x -> batches spread across XCDs
  int wid = tid >> 6;
  int lane = tid & 63;
  int lq = lane & 31;
  int h = lane >> 5;
  int q0 = blockIdx.y * 64 + wid * 32;

  // Q fragments (B-operand): B[k=c][n=q], lane: n=lq, k = kk*16 + h*8 + r
  short8 qf[8];
  const ushort* qp = qT + (((size_t)b << 12) + q0 + lq) * 128 + h * 8;
#pragma unroll
  for (int kk = 0; kk < 8; ++kk) qf[kk] = *(const short8*)(qp + kk * 16);

  f32x16 pacc[4];
#pragma unroll
  for (int nt = 0; nt < 4; ++nt)
#pragma unroll
    for (int r = 0; r < 16; ++r) pacc[nt][r] = 0.f;
  float m_run = -1e30f, l_run = 0.f;

  for (int t = 0; t < NPIX / 64; ++t) {
    int j0 = t << 6;
    __syncthreads();
    stage_tiles(kT, vB, lds, b, j0, tid);
    __syncthreads();

    // ---- QK^T (swapped): D[j][q] = K-tile * Q ----
    f32x16 s0, s1;
#pragma unroll
    for (int r = 0; r < 16; ++r) { s0[r] = 0.f; s1[r] = 0.f; }
    __builtin_amdgcn_s_setprio(1);
#pragma unroll
    for (int kk = 0; kk < 8; ++kk) {
      int ch = (kk << 1) + h;
      int r0 = lq;
      int r1 = 32 + lq;
      short8 kf0 = *(const short8*)&lds[((r0 << 4) + (ch ^ (r0 & 7))) << 3];
      short8 kf1 = *(const short8*)&lds[((r1 << 4) + (ch ^ (r1 & 7))) << 3];
      s0 = __builtin_amdgcn_mfma_f32_32x32x16_bf16(kf0, qf[kk], s0, 0, 0, 0);
      s1 = __builtin_amdgcn_mfma_f32_32x32x16_bf16(kf1, qf[kk], s1, 0, 0, 0);
    }
    __builtin_amdgcn_s_setprio(0);

    // ---- online softmax (lane holds 32 j-values of column q=lq) ----
    float tmax = s0[0];
#pragma unroll
    for (int r = 1; r < 16; ++r) tmax = fmaxf(tmax, s0[r]);
#pragma unroll
    for (int r = 0; r < 16; ++r) tmax = fmaxf(tmax, s1[r]);
    tmax = fmaxf(tmax, __shfl_xor(tmax, 32));
    float mnew = fmaxf(m_run, tmax);
    float pf0[16], pf1[16];
    float sum = 0.f;
#pragma unroll
    for (int r = 0; r < 16; ++r) { pf0[r] = __expf(s0[r] - mnew); sum += pf0[r]; }
#pragma unroll
    for (int r = 0; r < 16; ++r) { pf1[r] = __expf(s1[r] - mnew); sum += pf1[r]; }
    sum += __shfl_xor(sum, 32);
    float alpha = __expf(m_run - mnew);
    m_run = mnew;
    l_run = l_run * alpha + sum;

    // ---- build PA fragments: A[q][j] for PV, 4 k-steps of 16 j ----
    short8 pa[4];
#pragma unroll
    for (int kk = 0; kk < 4; ++kk) {
      float v0, v1, v2, v3, v4, v5, v6, v7;
      if (kk < 2) {
        if ((kk & 1) == 0) { v0=pf0[0];v1=pf0[1];v2=pf0[2];v3=pf0[3];v4=pf0[4];v5=pf0[5];v6=pf0[6];v7=pf0[7]; }
        else              { v0=pf0[8];v1=pf0[9];v2=pf0[10];v3=pf0[11];v4=pf0[12];v5=pf0[13];v6=pf0[14];v7=pf0[15]; }
      } else {
        if ((kk & 1) == 0) { v0=pf1[0];v1=pf1[1];v2=pf1[2];v3=pf1[3];v4=pf1[4];v5=pf1[5];v6=pf1[6];v7=pf1[7]; }
        else              { v0=pf1[8];v1=pf1[9];v2=pf1[10];v3=pf1[11];v4=pf1[12];v5=pf1[13];v6=pf1[14];v7=pf1[15]; }
      }
      unsigned P0a = packbf(v0, v1), P0b = packbf(v2, v3);
      unsigned P1a = packbf(v4, v5), P1b = packbf(v6, v7);
      unsigned sA = h ? P0a : P1a, sB = h ? P0b : P1b;
      unsigned rA = (unsigned)__shfl_xor((int)sA, 32);
      unsigned rB = (unsigned)__shfl_xor((int)sB, 32);
      uint4 wv;
      wv.x = h ? rA : P0a;  wv.y = h ? rB : P0b;
      wv.z = h ? P1a : rA;  wv.w = h ? P1b : rB;
      pa[kk] = __builtin_bit_cast(short8, wv);
    }

    // ---- rescale accumulators by alpha (per output q-row) ----
#pragma unroll
    for (int r = 0; r < 16; ++r) {
      int qr = (r & 3) + ((r >> 2) << 3) + (h << 2);
      float av = __shfl(alpha, qr);
      pacc[0][r] *= av; pacc[1][r] *= av; pacc[2][r] *= av; pacc[3][r] *= av;
    }

    // ---- PV: D[q][c] += P * V^T ----
    __builtin_amdgcn_s_setprio(1);
#pragma unroll
    for (int nt = 0; nt < 4; ++nt) {
      int row = (nt << 5) + lq;
#pragma unroll
      for (int kk = 0; kk < 4; ++kk) {
        int ch = (kk << 1) + h;
        short8 vf = *(const short8*)&lds[8192 + (((row << 3) + (ch ^ (row & 7))) << 3)];
        pacc[nt] = __builtin_amdgcn_mfma_f32_32x32x16_bf16(pa[kk], vf, pacc[nt], 0, 0, 0);
      }
    }
    __builtin_amdgcn_s_setprio(0);
  }

  // ---- epilogue: divide by l, store attOut[b][n][c] fp32 ----
  float invl = 1.f / l_run;
#pragma unroll
  for (int r = 0; r < 16; ++r) {
    int qr = (r & 3) + ((r >> 2) << 3) + (h << 2);
    float iv = __shfl(invl, qr);
    size_t rowbase = ((((size_t)b << 12) + q0 + qr) << 7) + lq;
    attOut[rowbase]      = pacc[0][r] * iv;
    attOut[rowbase + 32] = pacc[1][r] * iv;
    attOut[rowbase + 64] = pacc[2][r] * iv;
    attOut[rowbase + 96] = pacc[3][r] * iv;
  }
}

// ---------------- K4: proj 1x1 conv + bias + residual ------------------------
// reads attOut[b][n][c], writes d_out[b][o][n] = x + W*att + bias
__global__ __launch_bounds__(256) void k_proj(const float* __restrict__ x,
                                              const float* __restrict__ att,
                                              const float* __restrict__ w,
                                              const float* __restrict__ bias,
                                              float* __restrict__ out) {
  __shared__ float As[128][129];
  __shared__ float Bs[128][68];
  int b = blockIdx.y, p0 = blockIdx.x * 64;
  int tid = threadIdx.x;
  for (int i = tid; i < 128 * 128; i += 256) {
    As[i >> 7][i & 127] = w[i];
  }
  for (int i = tid; i < 64 * 128; i += 256) {
    int p = i >> 7, c = i & 127;
    Bs[c][p] = att[((((size_t)b << 12) + p0 + p) << 7) + c];
  }
  __syncthreads();
  int ty = tid >> 4, tx = tid & 15;  // o = ty*8.., p = tx*4..
  float acc[8][4] = {};
  for (int k = 0; k < 128; ++k) {
    float4 bv = *(const float4*)&Bs[k][tx * 4];
#pragma unroll
    for (int i = 0; i < 8; ++i) {
      float a = As[ty * 8 + i][k];
      acc[i][0] += a * bv.x; acc[i][1] += a * bv.y;
      acc[i][2] += a * bv.z; acc[i][3] += a * bv.w;
    }
  }
  const float* xb = x + (size_t)b * NC * NPIX;
  float* ob = out + (size_t)b * NC * NPIX;
#pragma unroll
  for (int i = 0; i < 8; ++i) {
    int o = ty * 8 + i;
    float bb = bias[o];
    size_t base = (size_t)o * NPIX + p0 + tx * 4;
    float4 xr = *(const float4*)&xb[base];
    float4 r = make_float4(acc[i][0] + bb + xr.x, acc[i][1] + bb + xr.y,
                           acc[i][2] + bb + xr.z, acc[i][3] + bb + xr.w);
    *(float4*)&ob[base] = r;
  }
}

extern "C" void kernel_launch(void* const* d_in, const int* in_sizes, int n_in,
                              void* d_out, int out_size, void* d_ws, size_t ws_size,
                              hipStream_t stream) {
  const float* x      = (const float*)d_in[0];
  const float* gamma  = (const float*)d_in[1];
  const float* beta   = (const float*)d_in[2];
  const float* w_qkv  = (const float*)d_in[3];
  const float* b_qkv  = (const float*)d_in[4];
  const float* w_proj = (const float*)d_in[5];
  const float* b_proj = (const float*)d_in[6];
  float* out = (float*)d_out;
  char* wsb = (char*)d_ws;

  float*  stats  = (float*)wsb;                       // 128*2 floats
  ushort* qT     = (ushort*)(wsb + 1024);             // 8MB
  ushort* kT     = (ushort*)(wsb + 1024 + (8u << 20));
  ushort* vB     = (ushort*)(wsb + 1024 + (16u << 20));
  float*  attOut = (float*)(wsb + 1024 + (24u << 20)); // 16MB

  hipLaunchKernelGGL(k_gn_stats, dim3(NB * NGROUP), dim3(256), 0, stream, x, stats);
  hipLaunchKernelGGL(k_qkv, dim3(NPIX / 64, 6, NB), dim3(256), 0, stream,
                     x, stats, gamma, beta, w_qkv, b_qkv, qT, kT, vB);
  hipLaunchKernelGGL(k_attn, dim3(NB, NPIX / 64), dim3(128), 0, stream,
                     qT, kT, vB, attOut);
  hipLaunchKernelGGL(k_proj, dim3(NPIX / 64, NB), dim3(256), 0, stream,
                     x, attOut, w_proj, b_proj, out);
}